// Round 1
// baseline (124.076 us; speedup 1.0000x reference)
//
#include <hip/hip_runtime.h>

#define NB   8
#define ND   64
#define NP   1024
#define KDIM 128
#define HID  256
#define OUTD 256

__device__ __forceinline__ float tanh_fast(float x) {
    // tanh(x) = 1 - 2/(exp(2x)+1);  exp(2x) = exp2(x * 2*log2(e))
    float e = __builtin_amdgcn_exp2f(x * 2.885390081777927f);
    return 1.0f - 2.0f * __builtin_amdgcn_rcpf(e + 1.0f);
}

// K1: hd/fd projections. One block per (b,i) row, thread = h.
__global__ __launch_bounds__(256) void k_proj_d(
    const float* __restrict__ Xd, const float* __restrict__ Wd,
    const float* __restrict__ Wa, float* __restrict__ hd, float* __restrict__ fd) {
    int row = blockIdx.x;            // b*64 + i
    int h = threadIdx.x;
    __shared__ float xs[KDIM];
    if (h < KDIM) xs[h] = Xd[row * KDIM + h];
    __syncthreads();
    float a1 = 0.f, a2 = 0.f;
#pragma unroll 8
    for (int k = 0; k < KDIM; ++k) {
        float x = xs[k];
        a1 = fmaf(x, Wd[k * HID + h], a1);
        a2 = fmaf(x, Wa[k * HID + h], a2);
    }
    hd[row * HID + h] = a1;
    fd[row * HID + h] = a2;
}

// K2: hp/fp projections. Block = (b, tile of 16 j). thread = h.
__global__ __launch_bounds__(256) void k_proj_p(
    const float* __restrict__ Xp, const float* __restrict__ Wp,
    const float* __restrict__ Wb, float* __restrict__ hp, float* __restrict__ fp) {
    int blk = blockIdx.x;            // b*64 + jt
    int b = blk >> 6, jt = blk & 63;
    int j0 = jt * 16;
    int t = threadIdx.x;             // h
    __shared__ float xs[16 * KDIM];  // 8 KB
    for (int idx = t; idx < 16 * KDIM; idx += 256)
        xs[idx] = Xp[(b * NP + j0) * KDIM + idx];   // 16 contiguous rows
    __syncthreads();
    float aH[16], aF[16];
#pragma unroll
    for (int jl = 0; jl < 16; ++jl) { aH[jl] = 0.f; aF[jl] = 0.f; }
    for (int k = 0; k < KDIM; ++k) {
        float wp = Wp[k * HID + t];
        float wb = Wb[k * HID + t];
#pragma unroll
        for (int jl = 0; jl < 16; ++jl) {
            float x = xs[jl * KDIM + k];
            aH[jl] = fmaf(x, wp, aH[jl]);
            aF[jl] = fmaf(x, wb, aF[jl]);
        }
    }
#pragma unroll
    for (int jl = 0; jl < 16; ++jl) {
        hp[(b * NP + j0 + jl) * HID + t] = aH[jl];
        fp[(b * NP + j0 + jl) * HID + t] = aF[jl];
    }
}

// K3: scores[b,i,j] = sum_h tanh(hd+hp)*w.  Block = (b, i-half(32), j-tile(32)).
// thread: il = t&31 (i within half), jg = t>>5 handles j = jg + 8*kk.
__global__ __launch_bounds__(256) void k_scores(
    const float* __restrict__ hd, const float* __restrict__ hp,
    const float* __restrict__ wsc, float* __restrict__ S) {
    int blk = blockIdx.x;            // b*64 + ih*32 + jt
    int b = blk >> 6, r = blk & 63, ih = r >> 5, jt = r & 31;
    int t = threadIdx.x;
    int il = t & 31, jg = t >> 5;
    __shared__ float hds[32 * HID];  // 32 KB, chunk-XOR-swizzled per row
    __shared__ float hps[32 * HID];  // 32 KB, plain [jl][h]
    __shared__ float wss[HID];       // 1 KB

    for (int idx = t; idx < 32 * HID; idx += 256) {
        int il2 = idx >> 8, h = idx & 255;
        float v = hd[((b * ND + ih * 32 + il2) << 8) + h];
        int h4 = h >> 2;
        hds[(il2 << 8) + (((h4 ^ (il2 & 7)) << 2) | (h & 3))] = v;
    }
    for (int idx = t; idx < 32 * HID; idx += 256)
        hps[idx] = hp[((b * NP + jt * 32) << 8) + idx];   // 32 contiguous rows
    if (t < HID) wss[t] = wsc[t];
    __syncthreads();

    const float4* hd4 = (const float4*)hds;   // idx: il*64 + swizzled chunk
    const float4* hp4 = (const float4*)hps;   // idx: jl*64 + chunk
    const float4* ws4 = (const float4*)wss;
    int sw = il & 7;
    float acc0 = 0.f, acc1 = 0.f, acc2 = 0.f, acc3 = 0.f;
    for (int h4 = 0; h4 < 64; ++h4) {
        float4 hv = hd4[(il << 6) + (h4 ^ sw)];
        float4 wv = ws4[h4];
        float4 p0 = hp4[((jg + 0) << 6) + h4];
        float4 p1 = hp4[((jg + 8) << 6) + h4];
        float4 p2 = hp4[((jg + 16) << 6) + h4];
        float4 p3 = hp4[((jg + 24) << 6) + h4];
        acc0 = fmaf(tanh_fast(hv.x + p0.x), wv.x, acc0);
        acc0 = fmaf(tanh_fast(hv.y + p0.y), wv.y, acc0);
        acc0 = fmaf(tanh_fast(hv.z + p0.z), wv.z, acc0);
        acc0 = fmaf(tanh_fast(hv.w + p0.w), wv.w, acc0);
        acc1 = fmaf(tanh_fast(hv.x + p1.x), wv.x, acc1);
        acc1 = fmaf(tanh_fast(hv.y + p1.y), wv.y, acc1);
        acc1 = fmaf(tanh_fast(hv.z + p1.z), wv.z, acc1);
        acc1 = fmaf(tanh_fast(hv.w + p1.w), wv.w, acc1);
        acc2 = fmaf(tanh_fast(hv.x + p2.x), wv.x, acc2);
        acc2 = fmaf(tanh_fast(hv.y + p2.y), wv.y, acc2);
        acc2 = fmaf(tanh_fast(hv.z + p2.z), wv.z, acc2);
        acc2 = fmaf(tanh_fast(hv.w + p2.w), wv.w, acc2);
        acc3 = fmaf(tanh_fast(hv.x + p3.x), wv.x, acc3);
        acc3 = fmaf(tanh_fast(hv.y + p3.y), wv.y, acc3);
        acc3 = fmaf(tanh_fast(hv.z + p3.z), wv.z, acc3);
        acc3 = fmaf(tanh_fast(hv.w + p3.w), wv.w, acc3);
    }
    int i = ih * 32 + il;
    int base = ((b * ND + i) << 10) + jt * 32 + jg;
    S[base + 0]  = acc0;
    S[base + 8]  = acc1;
    S[base + 16] = acc2;
    S[base + 24] = acc3;
}

// K4: softmax over j (1024) per (b,i) row, in place.
__global__ __launch_bounds__(256) void k_softmax(float* __restrict__ S) {
    int row = blockIdx.x;
    int t = threadIdx.x;
    float* Srow = S + (row << 10);
    float4 v = ((float4*)Srow)[t];
    __shared__ float red[256];
    float m = fmaxf(fmaxf(v.x, v.y), fmaxf(v.z, v.w));
    red[t] = m; __syncthreads();
    for (int s = 128; s > 0; s >>= 1) {
        if (t < s) red[t] = fmaxf(red[t], red[t + s]);
        __syncthreads();
    }
    m = red[0]; __syncthreads();
    const float L2E = 1.4426950408889634f;
    v.x = __builtin_amdgcn_exp2f((v.x - m) * L2E);
    v.y = __builtin_amdgcn_exp2f((v.y - m) * L2E);
    v.z = __builtin_amdgcn_exp2f((v.z - m) * L2E);
    v.w = __builtin_amdgcn_exp2f((v.w - m) * L2E);
    red[t] = (v.x + v.y) + (v.z + v.w); __syncthreads();
    for (int s = 128; s > 0; s >>= 1) {
        if (t < s) red[t] += red[t + s];
        __syncthreads();
    }
    float rinv = __builtin_amdgcn_rcpf(red[0]);
    v.x *= rinv; v.y *= rinv; v.z *= rinv; v.w *= rinv;
    ((float4*)Srow)[t] = v;
}

// K5: partial[blk][o] = sum over j-tile(16), all i of A*tanh(fd+fp).
// Block = (b, jt). thread: o4 = t&63 (4 o's), jq = t>>6 (4 j's).
__global__ __launch_bounds__(256) void k_facc(
    const float* __restrict__ fd, const float* __restrict__ fp,
    const float* __restrict__ A, float* __restrict__ part) {
    int blk = blockIdx.x;            // b*64 + jt
    int b = blk >> 6, jt = blk & 63;
    int j0 = jt * 16;
    int t = threadIdx.x;
    int o4 = t & 63, jq = t >> 6;
    __shared__ float fds[ND * OUTD];   // 64 KB
    __shared__ float as[ND * 16];      // 4 KB
    __shared__ float4 red[256];        // 4 KB

    for (int idx = t; idx < ND * OUTD; idx += 256)
        fds[idx] = fd[b * ND * OUTD + idx];
    for (int idx = t; idx < ND * 16; idx += 256) {
        int i = idx >> 4, jl = idx & 15;
        as[idx] = A[((b * ND + i) << 10) + j0 + jl];
    }
    __syncthreads();

    const float4* fd4 = (const float4*)fds;                       // i*64 + o4
    const float4* fp4 = (const float4*)(fp + ((b * NP + j0) << 8)); // jl*64 + o4
    float4 acc = {0.f, 0.f, 0.f, 0.f};
#pragma unroll
    for (int jj = 0; jj < 4; ++jj) {
        int jl = jq * 4 + jj;
        float4 fv = fp4[(jl << 6) + o4];
#pragma unroll 4
        for (int i = 0; i < ND; ++i) {
            float a = as[(i << 4) + jl];
            float4 dv = fd4[(i << 6) + o4];
            acc.x = fmaf(a, tanh_fast(dv.x + fv.x), acc.x);
            acc.y = fmaf(a, tanh_fast(dv.y + fv.y), acc.y);
            acc.z = fmaf(a, tanh_fast(dv.z + fv.z), acc.z);
            acc.w = fmaf(a, tanh_fast(dv.w + fv.w), acc.w);
        }
    }
    red[t] = acc; __syncthreads();
    if (t < 64) {
        float4 r0 = red[t], r1 = red[64 + t], r2 = red[128 + t], r3 = red[192 + t];
        float4 s;
        s.x = (r0.x + r1.x) + (r2.x + r3.x);
        s.y = (r0.y + r1.y) + (r2.y + r3.y);
        s.z = (r0.z + r1.z) + (r2.z + r3.z);
        s.w = (r0.w + r1.w) + (r2.w + r3.w);
        ((float4*)part)[(blk << 6) + t] = s;
    }
}

// K6: out[b][o] = sum over 64 jt-partials. Deterministic.
__global__ __launch_bounds__(256) void k_reduce(
    const float* __restrict__ part, float* __restrict__ out) {
    int b = blockIdx.x;
    int t = threadIdx.x;
    float s = 0.f;
    for (int jt = 0; jt < 64; ++jt)
        s += part[((b * 64 + jt) << 8) + t];
    out[(b << 8) + t] = s;
}

extern "C" void kernel_launch(void* const* d_in, const int* in_sizes, int n_in,
                              void* d_out, int out_size, void* d_ws, size_t ws_size,
                              hipStream_t stream) {
    const float* Xd  = (const float*)d_in[0];
    const float* Xp  = (const float*)d_in[1];
    const float* Wd  = (const float*)d_in[2];
    const float* Wp  = (const float*)d_in[3];
    const float* Wa  = (const float*)d_in[4];
    const float* Wb  = (const float*)d_in[5];
    const float* wsc = (const float*)d_in[6];
    float* out = (float*)d_out;

    float* ws = (float*)d_ws;
    float* hd   = ws;                       // 8*64*256   = 131072
    float* fd   = hd + NB * ND * HID;       // 131072
    float* hp   = fd + NB * ND * OUTD;      // 8*1024*256 = 2097152
    float* fp   = hp + NB * NP * HID;       // 2097152
    float* S    = fp + NB * NP * OUTD;      // 8*64*1024  = 524288
    float* part = S + NB * ND * NP;         // 512*256    = 131072
    // total ~19.5 MB of workspace

    k_proj_d<<<NB * ND, 256, 0, stream>>>(Xd, Wd, Wa, hd, fd);
    k_proj_p<<<NB * 64, 256, 0, stream>>>(Xp, Wp, Wb, hp, fp);
    k_scores<<<NB * 64, 256, 0, stream>>>(hd, hp, wsc, S);
    k_softmax<<<NB * ND, 256, 0, stream>>>(S);
    k_facc<<<NB * 64, 256, 0, stream>>>(fd, fp, S, part);
    k_reduce<<<NB, 256, 0, stream>>>(part, out);
}

// Round 2
// 97.374 us; speedup vs baseline: 1.2742x; 1.2742x over previous
//
#include <hip/hip_runtime.h>

#define NB   8
#define ND   64
#define NP   1024
#define KDIM 128
#define HID  256
#define OUTD 256
#define CSC  2.885390081777927f   // 2*log2(e)

// a = 2*log2(e)*x  ->  1/(1 + e^(2x));  tanh(x) = 1 - 2*sigr
__device__ __forceinline__ float sigr(float a) {
    return __builtin_amdgcn_rcpf(1.0f + __builtin_amdgcn_exp2f(a));
}

// K1: all four projections, pre-scaled by CSC. 8 rows per block.
// blocks [0, 1024): protein side (hp, fp). blocks [1024, 1088): drug side (hd, fd).
__global__ __launch_bounds__(256) void k_proj(
    const float* __restrict__ Xd, const float* __restrict__ Xp,
    const float* __restrict__ Wd, const float* __restrict__ Wa,
    const float* __restrict__ Wp, const float* __restrict__ Wb,
    float* __restrict__ hd, float* __restrict__ fd,
    float* __restrict__ hp, float* __restrict__ fp) {
    int blk = blockIdx.x, t = threadIdx.x;
    const float *X, *W1, *W2;
    float *O1, *O2;
    int row0;
    if (blk < NB * 128) {
        int b = blk >> 7, jt = blk & 127;
        row0 = b * NP + jt * 8; X = Xp; W1 = Wp; W2 = Wb; O1 = hp; O2 = fp;
    } else {
        int r = blk - NB * 128;
        int b = r >> 3, it = r & 7;
        row0 = b * ND + it * 8; X = Xd; W1 = Wd; W2 = Wa; O1 = hd; O2 = fd;
    }
    __shared__ float4 xs[256];          // 8 rows x 128 k = 4 KB
    xs[t] = ((const float4*)(X + row0 * KDIM))[t];
    __syncthreads();
    float aH[8], aF[8];
#pragma unroll
    for (int r = 0; r < 8; ++r) { aH[r] = 0.f; aF[r] = 0.f; }
    for (int k4 = 0; k4 < 32; ++k4) {
        int k = k4 << 2;
        float w10 = W1[(k + 0) * HID + t], w11 = W1[(k + 1) * HID + t];
        float w12 = W1[(k + 2) * HID + t], w13 = W1[(k + 3) * HID + t];
        float w20 = W2[(k + 0) * HID + t], w21 = W2[(k + 1) * HID + t];
        float w22 = W2[(k + 2) * HID + t], w23 = W2[(k + 3) * HID + t];
#pragma unroll
        for (int r = 0; r < 8; ++r) {
            float4 x = xs[(r << 5) + k4];   // broadcast b128
            aH[r] = fmaf(x.x, w10, aH[r]); aH[r] = fmaf(x.y, w11, aH[r]);
            aH[r] = fmaf(x.z, w12, aH[r]); aH[r] = fmaf(x.w, w13, aH[r]);
            aF[r] = fmaf(x.x, w20, aF[r]); aF[r] = fmaf(x.y, w21, aF[r]);
            aF[r] = fmaf(x.z, w22, aF[r]); aF[r] = fmaf(x.w, w23, aF[r]);
        }
    }
#pragma unroll
    for (int r = 0; r < 8; ++r) {
        O1[(row0 + r) * HID + t] = aH[r] * CSC;
        O2[(row0 + r) * HID + t] = aF[r] * CSC;
    }
}

// K2: shifted scores S[b,i,j] = sum_h (-2 w_h) * sigr(hd'+hp')   (softmax is
// shift-invariant so the dropped constant sum_h w_h doesn't matter).
// Tile 16 i x 16 j. grid = 8 * 4 * 64 = 2048.
__global__ __launch_bounds__(256) void k_scores(
    const float* __restrict__ hd, const float* __restrict__ hp,
    const float* __restrict__ wsc, float* __restrict__ S) {
    int blk = blockIdx.x;
    int b = blk >> 8, r = blk & 255, ih = r >> 6, jt = r & 63;
    int t = threadIdx.x;
    __shared__ float4 hds[16 * 64];   // 16 KB, chunk-XOR swizzled
    __shared__ float4 hps[16 * 64];   // 16 KB
    __shared__ float  w2s[HID];       // 1 KB
    const float4* hdg = (const float4*)(hd + ((b * ND + ih * 16) << 8));
#pragma unroll
    for (int n = 0; n < 4; ++n) {
        int idx = t + (n << 8);
        int row = idx >> 6, ch = idx & 63;
        hds[(row << 6) + (ch ^ (row & 7))] = hdg[idx];
    }
    const float4* hpg = (const float4*)(hp + ((b * NP + jt * 16) << 8));
#pragma unroll
    for (int n = 0; n < 4; ++n) hps[t + (n << 8)] = hpg[t + (n << 8)];
    w2s[t] = -2.0f * wsc[t];
    __syncthreads();

    int il = t & 15, jg = t >> 4;
    const float4* hv4 = hds + (il << 6);
    const float4* pv4 = hps + (jg << 6);
    const float4* w4  = (const float4*)w2s;
    int sw = il & 7;
    float acc = 0.f;
    for (int h4 = 0; h4 < 64; ++h4) {
        float4 hv = hv4[h4 ^ sw];
        float4 wv = w4[h4];
        float4 pv = pv4[h4];
        acc = fmaf(wv.x, sigr(hv.x + pv.x), acc);
        acc = fmaf(wv.y, sigr(hv.y + pv.y), acc);
        acc = fmaf(wv.z, sigr(hv.z + pv.z), acc);
        acc = fmaf(wv.w, sigr(hv.w + pv.w), acc);
    }
    int i = ih * 16 + il;
    S[((b * ND + i) << 10) + jt * 16 + jg] = acc;
}

// K3: softmax over j per (b,i) row, in place; writes A2 = -2*A.
__global__ __launch_bounds__(256) void k_softmax(float* __restrict__ S) {
    int row = blockIdx.x;
    int t = threadIdx.x;
    float* Srow = S + (row << 10);
    float4 v = ((float4*)Srow)[t];
    __shared__ float red[256];
    float m = fmaxf(fmaxf(v.x, v.y), fmaxf(v.z, v.w));
    red[t] = m; __syncthreads();
    for (int s = 128; s > 0; s >>= 1) {
        if (t < s) red[t] = fmaxf(red[t], red[t + s]);
        __syncthreads();
    }
    m = red[0]; __syncthreads();
    const float L2E = 1.4426950408889634f;
    v.x = __builtin_amdgcn_exp2f((v.x - m) * L2E);
    v.y = __builtin_amdgcn_exp2f((v.y - m) * L2E);
    v.z = __builtin_amdgcn_exp2f((v.z - m) * L2E);
    v.w = __builtin_amdgcn_exp2f((v.w - m) * L2E);
    red[t] = (v.x + v.y) + (v.z + v.w); __syncthreads();
    for (int s = 128; s > 0; s >>= 1) {
        if (t < s) red[t] += red[t + s];
        __syncthreads();
    }
    float sneg = -2.0f * __builtin_amdgcn_rcpf(red[0]);   // A2 = -2*A
    v.x *= sneg; v.y *= sneg; v.z *= sneg; v.w *= sneg;
    ((float4*)Srow)[t] = v;
}

// K4: partial[blk][o] = sum_{i in 32, j in 16} A2 * sigr(fd'+fp').
// (X_int = 64 + sum of all partials, since sum_j A = 1 per i.)
// grid = 8 * 2 * 64 = 1024.
__global__ __launch_bounds__(256) void k_facc(
    const float* __restrict__ fd, const float* __restrict__ fp,
    const float* __restrict__ A2, float* __restrict__ part) {
    int blk = blockIdx.x;
    int b = blk >> 7, rr = blk & 127, ih = rr >> 6, jt = rr & 63;
    int i0 = ih * 32, j0 = jt * 16;
    int t = threadIdx.x;
    __shared__ float4 fds[32 * 64];   // 32 KB
    __shared__ float4 as4[32 * 4];    // 2 KB  (A2 tile [32 i][16 j])
    __shared__ float4 red[256];       // 4 KB
    const float4* fdg = (const float4*)(fd + ((b * ND + i0) << 8));
#pragma unroll
    for (int n = 0; n < 8; ++n) fds[t + (n << 8)] = fdg[t + (n << 8)];
    if (t < 128) {
        int ii = t >> 2, jq = t & 3;
        as4[t] = ((const float4*)A2)[((b * ND + i0 + ii) << 8) + (j0 >> 2) + jq];
    }
    __syncthreads();

    int o4 = t & 63, jq = t >> 6;
    const float4* fpg = (const float4*)(fp + ((b * NP + j0 + (jq << 2)) << 8));
    float4 fv0 = fpg[o4], fv1 = fpg[64 + o4], fv2 = fpg[128 + o4], fv3 = fpg[192 + o4];
    float4 acc = {0.f, 0.f, 0.f, 0.f};
    for (int i = 0; i < 32; ++i) {
        float4 dv = fds[(i << 6) + o4];
        float4 a  = as4[(i << 2) + jq];
        acc.x = fmaf(a.x, sigr(dv.x + fv0.x), acc.x);
        acc.y = fmaf(a.x, sigr(dv.y + fv0.y), acc.y);
        acc.z = fmaf(a.x, sigr(dv.z + fv0.z), acc.z);
        acc.w = fmaf(a.x, sigr(dv.w + fv0.w), acc.w);
        acc.x = fmaf(a.y, sigr(dv.x + fv1.x), acc.x);
        acc.y = fmaf(a.y, sigr(dv.y + fv1.y), acc.y);
        acc.z = fmaf(a.y, sigr(dv.z + fv1.z), acc.z);
        acc.w = fmaf(a.y, sigr(dv.w + fv1.w), acc.w);
        acc.x = fmaf(a.z, sigr(dv.x + fv2.x), acc.x);
        acc.y = fmaf(a.z, sigr(dv.y + fv2.y), acc.y);
        acc.z = fmaf(a.z, sigr(dv.z + fv2.z), acc.z);
        acc.w = fmaf(a.z, sigr(dv.w + fv2.w), acc.w);
        acc.x = fmaf(a.w, sigr(dv.x + fv3.x), acc.x);
        acc.y = fmaf(a.w, sigr(dv.y + fv3.y), acc.y);
        acc.z = fmaf(a.w, sigr(dv.z + fv3.z), acc.z);
        acc.w = fmaf(a.w, sigr(dv.w + fv3.w), acc.w);
    }
    red[t] = acc; __syncthreads();
    if (t < 64) {
        float4 r0 = red[t], r1 = red[64 + t], r2 = red[128 + t], r3 = red[192 + t];
        float4 s;
        s.x = (r0.x + r1.x) + (r2.x + r3.x);
        s.y = (r0.y + r1.y) + (r2.y + r3.y);
        s.z = (r0.z + r1.z) + (r2.z + r3.z);
        s.w = (r0.w + r1.w) + (r2.w + r3.w);
        ((float4*)part)[(blk << 6) + t] = s;
    }
}

// K5: out[b][o] = 64 + sum over 128 partials. Deterministic.
__global__ __launch_bounds__(256) void k_reduce(
    const float* __restrict__ part, float* __restrict__ out) {
    int b = blockIdx.x;
    int t = threadIdx.x;
    float s = 64.0f;   // sum_i sum_j A_ij * 1
    for (int q = 0; q < 128; ++q)
        s += part[((b * 128 + q) << 8) + t];
    out[(b << 8) + t] = s;
}

extern "C" void kernel_launch(void* const* d_in, const int* in_sizes, int n_in,
                              void* d_out, int out_size, void* d_ws, size_t ws_size,
                              hipStream_t stream) {
    const float* Xd  = (const float*)d_in[0];
    const float* Xp  = (const float*)d_in[1];
    const float* Wd  = (const float*)d_in[2];
    const float* Wp  = (const float*)d_in[3];
    const float* Wa  = (const float*)d_in[4];
    const float* Wb  = (const float*)d_in[5];
    const float* wsc = (const float*)d_in[6];
    float* out = (float*)d_out;

    float* ws = (float*)d_ws;
    float* hd   = ws;                       // 131072
    float* fd   = hd + NB * ND * HID;       // 131072
    float* hp   = fd + NB * ND * OUTD;      // 2097152
    float* fp   = hp + NB * NP * HID;       // 2097152
    float* S    = fp + NB * NP * OUTD;      // 524288
    float* part = hp;                       // overlay: hp dead after k_scores; 262144 needed

    k_proj   <<<NB * 128 + NB * 8, 256, 0, stream>>>(Xd, Xp, Wd, Wa, Wp, Wb, hd, fd, hp, fp);
    k_scores <<<NB * 256, 256, 0, stream>>>(hd, hp, wsc, S);
    k_softmax<<<NB * ND, 256, 0, stream>>>(S);
    k_facc   <<<NB * 128, 256, 0, stream>>>(fd, fp, S, part);
    k_reduce <<<NB, 256, 0, stream>>>(part, out);
}

// Round 3
// 95.697 us; speedup vs baseline: 1.2965x; 1.0175x over previous
//
#include <hip/hip_runtime.h>

#define NB   8
#define ND   64
#define NP   1024
#define KDIM 128
#define HID  256
#define OUTD 256
#define CSC  2.885390081777927f   // 2*log2(e)

// a = 2*log2(e)*x  ->  sigr(a) = 1/(1 + e^(2x));  tanh(x) = 1 - 2*sigr
__device__ __forceinline__ float sigr(float a) {
    return __builtin_amdgcn_rcpf(1.0f + __builtin_amdgcn_exp2f(a));
}

// K1: all four projections, pre-scaled by CSC. 8 rows per block.
// blocks [0, 1024): protein side (hp, fp). blocks [1024, 1088): drug side (hd, fd).
__global__ __launch_bounds__(256) void k_proj(
    const float* __restrict__ Xd, const float* __restrict__ Xp,
    const float* __restrict__ Wd, const float* __restrict__ Wa,
    const float* __restrict__ Wp, const float* __restrict__ Wb,
    float* __restrict__ hd, float* __restrict__ fd,
    float* __restrict__ hp, float* __restrict__ fp) {
    int blk = blockIdx.x, t = threadIdx.x;
    const float *X, *W1, *W2;
    float *O1, *O2;
    int row0;
    if (blk < NB * 128) {
        int b = blk >> 7, jt = blk & 127;
        row0 = b * NP + jt * 8; X = Xp; W1 = Wp; W2 = Wb; O1 = hp; O2 = fp;
    } else {
        int r = blk - NB * 128;
        int b = r >> 3, it = r & 7;
        row0 = b * ND + it * 8; X = Xd; W1 = Wd; W2 = Wa; O1 = hd; O2 = fd;
    }
    __shared__ float4 xs[256];          // 8 rows x 128 k = 4 KB
    xs[t] = ((const float4*)(X + row0 * KDIM))[t];
    __syncthreads();
    float aH[8], aF[8];
#pragma unroll
    for (int r = 0; r < 8; ++r) { aH[r] = 0.f; aF[r] = 0.f; }
    for (int k4 = 0; k4 < 32; ++k4) {
        int k = k4 << 2;
        float w10 = W1[(k + 0) * HID + t], w11 = W1[(k + 1) * HID + t];
        float w12 = W1[(k + 2) * HID + t], w13 = W1[(k + 3) * HID + t];
        float w20 = W2[(k + 0) * HID + t], w21 = W2[(k + 1) * HID + t];
        float w22 = W2[(k + 2) * HID + t], w23 = W2[(k + 3) * HID + t];
#pragma unroll
        for (int r = 0; r < 8; ++r) {
            float4 x = xs[(r << 5) + k4];   // broadcast b128
            aH[r] = fmaf(x.x, w10, aH[r]); aH[r] = fmaf(x.y, w11, aH[r]);
            aH[r] = fmaf(x.z, w12, aH[r]); aH[r] = fmaf(x.w, w13, aH[r]);
            aF[r] = fmaf(x.x, w20, aF[r]); aF[r] = fmaf(x.y, w21, aF[r]);
            aF[r] = fmaf(x.z, w22, aF[r]); aF[r] = fmaf(x.w, w23, aF[r]);
        }
    }
#pragma unroll
    for (int r = 0; r < 8; ++r) {
        O1[(row0 + r) * HID + t] = aH[r] * CSC;
        O2[(row0 + r) * HID + t] = aF[r] * CSC;
    }
}

// K2: shifted scores S[b,i,j] = sum_h (-2 w_h) * sigr(hd'+hp').
// Tile 16 i x 32 j, 2 j per thread. grid = 8 * 4 * 32 = 1024.
// Thread map: jg = t&15 (j fast) -> coalesced stores, broadcast hd reads;
// hp in LDS chunk-XOR swizzled -> conflict-free full-rate reads.
__global__ __launch_bounds__(256) void k_scores(
    const float* __restrict__ hd, const float* __restrict__ hp,
    const float* __restrict__ wsc, float* __restrict__ S) {
    int blk = blockIdx.x;
    int b = blk >> 7, r = blk & 127, ih = r >> 5, jt = r & 31;
    int t = threadIdx.x;
    __shared__ float4 hds[16 * 64];   // 16 KB, plain (broadcast-read)
    __shared__ float4 hps[32 * 64];   // 32 KB, chunk-XOR swizzled
    __shared__ float  w2s[HID];       // 1 KB
    const float4* hdg = (const float4*)(hd + ((b * ND + ih * 16) << 8));
#pragma unroll
    for (int n = 0; n < 4; ++n) hds[t + (n << 8)] = hdg[t + (n << 8)];
    const float4* hpg = (const float4*)(hp + ((b * NP + jt * 32) << 8));
#pragma unroll
    for (int n = 0; n < 8; ++n) {
        int idx = t + (n << 8);
        int row = idx >> 6, ch = idx & 63;
        hps[(row << 6) + (ch ^ (row & 7))] = hpg[idx];
    }
    w2s[t] = -2.0f * wsc[t];
    __syncthreads();

    int jg = t & 15, il = t >> 4;
    const float4* hv4 = hds + (il << 6);
    const float4* p0v = hps + (jg << 6);
    const float4* p1v = hps + ((jg + 16) << 6);
    const float4* w4  = (const float4*)w2s;
    int sw = jg & 7;                  // (jg+16)&7 == jg&7
    float acc0 = 0.f, acc1 = 0.f;
    for (int h4 = 0; h4 < 64; ++h4) {
        float4 hv = hv4[h4];
        float4 wv = w4[h4];
        float4 p0 = p0v[h4 ^ sw];
        float4 p1 = p1v[h4 ^ sw];
        acc0 = fmaf(wv.x, sigr(hv.x + p0.x), acc0);
        acc0 = fmaf(wv.y, sigr(hv.y + p0.y), acc0);
        acc0 = fmaf(wv.z, sigr(hv.z + p0.z), acc0);
        acc0 = fmaf(wv.w, sigr(hv.w + p0.w), acc0);
        acc1 = fmaf(wv.x, sigr(hv.x + p1.x), acc1);
        acc1 = fmaf(wv.y, sigr(hv.y + p1.y), acc1);
        acc1 = fmaf(wv.z, sigr(hv.z + p1.z), acc1);
        acc1 = fmaf(wv.w, sigr(hv.w + p1.w), acc1);
    }
    int i = ih * 16 + il;
    int base = ((b * ND + i) << 10) + jt * 32 + jg;
    S[base]      = acc0;
    S[base + 16] = acc1;
}

// K3: softmax over j per (b,i) row, in place; writes A2 = -2*A.
// No max pass: |S| <= 2*sum|w| <= 32, exp2 arg <= ~46 -> fp32-safe.
__global__ __launch_bounds__(256) void k_softmax(float* __restrict__ S) {
    int row = blockIdx.x;
    int t = threadIdx.x;
    float* Srow = S + (row << 10);
    float4 v = ((float4*)Srow)[t];
    const float L2E = 1.4426950408889634f;
    v.x = __builtin_amdgcn_exp2f(v.x * L2E);
    v.y = __builtin_amdgcn_exp2f(v.y * L2E);
    v.z = __builtin_amdgcn_exp2f(v.z * L2E);
    v.w = __builtin_amdgcn_exp2f(v.w * L2E);
    float s4 = (v.x + v.y) + (v.z + v.w);
#pragma unroll
    for (int off = 32; off > 0; off >>= 1) s4 += __shfl_xor(s4, off, 64);
    __shared__ float wsum[4];
    if ((t & 63) == 0) wsum[t >> 6] = s4;
    __syncthreads();
    float tot = (wsum[0] + wsum[1]) + (wsum[2] + wsum[3]);
    float sneg = -2.0f * __builtin_amdgcn_rcpf(tot);   // A2 = -2*A
    v.x *= sneg; v.y *= sneg; v.z *= sneg; v.w *= sneg;
    ((float4*)Srow)[t] = v;
}

// K4: partial[blk][o] = sum_{i in 32, j in 16} A2 * sigr(fd'+fp').
// (X_int = 64 + sum of all partials, since sum_j A = 1 per i.)
// grid = 8 * 2 * 64 = 1024.
__global__ __launch_bounds__(256) void k_facc(
    const float* __restrict__ fd, const float* __restrict__ fp,
    const float* __restrict__ A2, float* __restrict__ part) {
    int blk = blockIdx.x;
    int b = blk >> 7, rr = blk & 127, ih = rr >> 6, jt = rr & 63;
    int i0 = ih * 32, j0 = jt * 16;
    int t = threadIdx.x;
    __shared__ float4 fds[32 * 64];   // 32 KB
    __shared__ float4 as4[32 * 4];    // 2 KB  (A2 tile [32 i][16 j])
    __shared__ float4 red[256];       // 4 KB
    const float4* fdg = (const float4*)(fd + ((b * ND + i0) << 8));
#pragma unroll
    for (int n = 0; n < 8; ++n) fds[t + (n << 8)] = fdg[t + (n << 8)];
    if (t < 128) {
        int ii = t >> 2, jq = t & 3;
        as4[t] = ((const float4*)A2)[((b * ND + i0 + ii) << 8) + (j0 >> 2) + jq];
    }
    __syncthreads();

    int o4 = t & 63, jq = t >> 6;
    const float4* fpg = (const float4*)(fp + ((b * NP + j0 + (jq << 2)) << 8));
    float4 fv0 = fpg[o4], fv1 = fpg[64 + o4], fv2 = fpg[128 + o4], fv3 = fpg[192 + o4];
    float4 acc = {0.f, 0.f, 0.f, 0.f};
    for (int i = 0; i < 32; ++i) {
        float4 dv = fds[(i << 6) + o4];
        float4 a  = as4[(i << 2) + jq];
        acc.x = fmaf(a.x, sigr(dv.x + fv0.x), acc.x);
        acc.y = fmaf(a.x, sigr(dv.y + fv0.y), acc.y);
        acc.z = fmaf(a.x, sigr(dv.z + fv0.z), acc.z);
        acc.w = fmaf(a.x, sigr(dv.w + fv0.w), acc.w);
        acc.x = fmaf(a.y, sigr(dv.x + fv1.x), acc.x);
        acc.y = fmaf(a.y, sigr(dv.y + fv1.y), acc.y);
        acc.z = fmaf(a.y, sigr(dv.z + fv1.z), acc.z);
        acc.w = fmaf(a.y, sigr(dv.w + fv1.w), acc.w);
        acc.x = fmaf(a.z, sigr(dv.x + fv2.x), acc.x);
        acc.y = fmaf(a.z, sigr(dv.y + fv2.y), acc.y);
        acc.z = fmaf(a.z, sigr(dv.z + fv2.z), acc.z);
        acc.w = fmaf(a.z, sigr(dv.w + fv2.w), acc.w);
        acc.x = fmaf(a.w, sigr(dv.x + fv3.x), acc.x);
        acc.y = fmaf(a.w, sigr(dv.y + fv3.y), acc.y);
        acc.z = fmaf(a.w, sigr(dv.z + fv3.z), acc.z);
        acc.w = fmaf(a.w, sigr(dv.w + fv3.w), acc.w);
    }
    red[t] = acc; __syncthreads();
    if (t < 64) {
        float4 r0 = red[t], r1 = red[64 + t], r2 = red[128 + t], r3 = red[192 + t];
        float4 s;
        s.x = (r0.x + r1.x) + (r2.x + r3.x);
        s.y = (r0.y + r1.y) + (r2.y + r3.y);
        s.z = (r0.z + r1.z) + (r2.z + r3.z);
        s.w = (r0.w + r1.w) + (r2.w + r3.w);
        ((float4*)part)[(blk << 6) + t] = s;
    }
}

// K5: out[b][o] = 64 + sum over 128 partials. Deterministic.
__global__ __launch_bounds__(256) void k_reduce(
    const float* __restrict__ part, float* __restrict__ out) {
    int b = blockIdx.x;
    int t = threadIdx.x;
    float s = 64.0f;   // sum_i sum_j A_ij * 1
    for (int q = 0; q < 128; ++q)
        s += part[((b * 128 + q) << 8) + t];
    out[(b << 8) + t] = s;
}

extern "C" void kernel_launch(void* const* d_in, const int* in_sizes, int n_in,
                              void* d_out, int out_size, void* d_ws, size_t ws_size,
                              hipStream_t stream) {
    const float* Xd  = (const float*)d_in[0];
    const float* Xp  = (const float*)d_in[1];
    const float* Wd  = (const float*)d_in[2];
    const float* Wp  = (const float*)d_in[3];
    const float* Wa  = (const float*)d_in[4];
    const float* Wb  = (const float*)d_in[5];
    const float* wsc = (const float*)d_in[6];
    float* out = (float*)d_out;

    float* ws = (float*)d_ws;
    float* hd   = ws;                       // 131072
    float* fd   = hd + NB * ND * HID;       // 131072
    float* hp   = fd + NB * ND * OUTD;      // 2097152
    float* fp   = hp + NB * NP * HID;       // 2097152
    float* S    = fp + NB * NP * OUTD;      // 524288
    float* part = hp;                       // overlay: hp dead after k_scores

    k_proj   <<<NB * 128 + NB * 8, 256, 0, stream>>>(Xd, Xp, Wd, Wa, Wp, Wb, hd, fd, hp, fp);
    k_scores <<<NB * 128, 256, 0, stream>>>(hd, hp, wsc, S);
    k_softmax<<<NB * ND, 256, 0, stream>>>(S);
    k_facc   <<<NB * 128, 256, 0, stream>>>(fd, fp, S, part);
    k_reduce <<<NB, 256, 0, stream>>>(part, out);
}